// Round 1
// baseline (470.421 us; speedup 1.0000x reference)
//
#include <hip/hip_runtime.h>

// ScaledDotProductAttention: context = softmax(relu(Q K^T) @ R / 8) @ V
// B=8, N=2048, D=64. R = (1+e)/(1+exp(1-dist)), shared across batch.
//
// ws layout (needs >= 74 MB):
//   [0,   64MB)  Ph  : fp16 relu(QK^T)*0.125, [B][N][N]
//   [64MB,72MB)  RhT : fp16 R^T, [m][k] (k = key index)
//   [72MB,74MB)  VhT : fp16 V^T, [B][64][N]

typedef _Float16 f16;
typedef _Float16 f16x8 __attribute__((ext_vector_type(8)));
typedef float    f32x4 __attribute__((ext_vector_type(4)));

#define AS1C(p) ((const __attribute__((address_space(1))) void*)(p))
#define AS3(p)  ((__attribute__((address_space(3))) void*)(p))

__device__ __forceinline__ f16x8 cvt_f16x8(float4 a, float4 b){
  f16x8 v;
  v[0]=(f16)a.x; v[1]=(f16)a.y; v[2]=(f16)a.z; v[3]=(f16)a.w;
  v[4]=(f16)b.x; v[5]=(f16)b.y; v[6]=(f16)b.z; v[7]=(f16)b.w;
  return v;
}

// ---------------- kernel 0a: RhT[m][k] = rescale(dist[k][m]) in fp16 -------
__global__ void k_rescaleT(const float* __restrict__ Dm, f16* __restrict__ RhT){
  __shared__ f16 tl[64][65];
  const int k0 = blockIdx.x*64, m0 = blockIdx.y*64;
  const int t = threadIdx.x, c = t & 63, g = t >> 6;
#pragma unroll
  for (int i=0;i<16;++i){
    int k = g*16 + i;
    float d = Dm[(size_t)(k0 + k)*2048 + m0 + c];
    tl[k][c] = (f16)(3.7182818284590452f / (1.0f + __expf(1.0f - d)));
  }
  __syncthreads();
#pragma unroll
  for (int i=0;i<16;++i){
    int m = g*16 + i;
    RhT[(size_t)(m0 + m)*2048 + k0 + c] = tl[c][m];
  }
}

// ---------------- kernel 0b: VhT[b][d][m] = V[b][m][d] in fp16 -------------
__global__ void k_vT(const float* __restrict__ V, f16* __restrict__ VhT){
  __shared__ f16 tl[64][65];
  const int b = blockIdx.y, m0 = blockIdx.x*64;
  const int t = threadIdx.x, c = t & 63, g = t >> 6;
#pragma unroll
  for (int i=0;i<16;++i){
    int m = g*16 + i;
    tl[m][c] = (f16)V[((size_t)b*2048 + m0 + m)*64 + c];
  }
  __syncthreads();
#pragma unroll
  for (int i=0;i<16;++i){
    int d = g*16 + i;
    VhT[((size_t)b*64 + d)*2048 + m0 + c] = tl[c][d];
  }
}

// ---------------- kernel 1: Ph = relu(Q K^T) * 0.125 in fp16 ---------------
// 128x128 tile per WG, 4 waves in 2x2, wave tile 64x64 (4x4 of 16x16x32).
// A/B fragments loaded directly from global (coalesced 16B/lane), K=64.
__launch_bounds__(256, 2)
__global__ void k_qk(const float* __restrict__ Q, const float* __restrict__ Km,
                     f16* __restrict__ Ph){
  const int t = threadIdx.x, w = t>>6, l = t&63, lr = l&15, q = l>>4;
  const int b = blockIdx.z;
  const int n0 = blockIdx.y*128, m0 = blockIdx.x*128;
  const int wr = (w>>1)*64, wc = (w&1)*64;
  const float* Qb = Q  + (size_t)b*2048*64;
  const float* Kb = Km + (size_t)b*2048*64;
  f32x4 acc[4][4] = {};
#pragma unroll
  for (int kc=0;kc<2;++kc){
    f16x8 af[4], bf[4];
    const int kof = kc*32 + q*8;
#pragma unroll
    for (int ti=0;ti<4;++ti){
      const float* p = Qb + (size_t)(n0 + wr + 16*ti + lr)*64 + kof;
      af[ti] = cvt_f16x8(*(const float4*)p, *(const float4*)(p+4));
    }
#pragma unroll
    for (int tj=0;tj<4;++tj){
      const float* p = Kb + (size_t)(m0 + wc + 16*tj + lr)*64 + kof;
      bf[tj] = cvt_f16x8(*(const float4*)p, *(const float4*)(p+4));
    }
#pragma unroll
    for (int ti=0;ti<4;++ti)
#pragma unroll
      for (int tj=0;tj<4;++tj)
        acc[ti][tj] = __builtin_amdgcn_mfma_f32_16x16x32_f16(af[ti], bf[tj], acc[ti][tj], 0,0,0);
  }
#pragma unroll
  for (int ti=0;ti<4;++ti)
#pragma unroll
    for (int tj=0;tj<4;++tj)
#pragma unroll
      for (int r=0;r<4;++r){
        int row = n0 + wr + 16*ti + 4*q + r;
        int col = m0 + wc + 16*tj + lr;
        float v = fmaxf(acc[ti][tj][r], 0.0f) * 0.125f;
        Ph[((size_t)b*2048 + row)*2048 + col] = (f16)v;
      }
}

// ---------------- kernel 2: flash attention over precomputed scores --------
// Per WG: 64 Q-rows, loop over 8 m-tiles of 256. S-tile = Ph(64x2048) @ RhT,
// K-chunks of 32 staged via global_load_lds (double buffered). 4 waves,
// each wave = 64 rows x 64 cols of the S-tile (col-split). Online softmax.
// LDS: Pbuf 8K | Rbuf 32K | El 33792 | Vl 33792 | stats 2560 = 111104 B.
__launch_bounds__(256, 1)
__global__ void k_attn(const f16* __restrict__ Ph, const f16* __restrict__ RhT,
                       const f16* __restrict__ VhT, float* __restrict__ out){
  extern __shared__ char smem[];
  f16*  Pbuf = (f16*)smem;                            // [2][64][32]
  f16*  Rbuf = (f16*)(smem + 8192);                   // [2][256][32]
  f16*  El   = (f16*)(smem + 8192 + 32768);           // [64][264]
  f16*  Vl   = (f16*)(smem + 8192 + 32768 + 33792);   // [64][264]
  float* stat_max = (float*)(smem + 8192 + 32768 + 2*33792); // [64][4]
  float* stat_sum = stat_max + 256;                   // [64][4]
  float* mrow = stat_sum + 256;                       // [64]
  float* lrow = mrow + 64;                            // [64]

  const int t = threadIdx.x, w = t>>6, l = t&63, lr = l&15, q = l>>4;
  const int b = blockIdx.y;
  const int n0 = blockIdx.x*64;
  const int prow = t >> 2, pk16 = t & 3;   // staging slot decode

  const f16* Pblk = Ph  + ((size_t)b*2048 + n0)*2048;
  const f16* Vb   = VhT + (size_t)b*64*2048;

  if (t < 64){ mrow[t] = -1e30f; lrow[t] = 0.0f; }
  f32x4 Oacc[4] = {};   // wave w owns O rows 16w..16w+15, col tiles tj
  __syncthreads();

  for (int mt = 0; mt < 8; ++mt){
    const int m0 = mt * 256;

    // prefetch V tile (VhT[d][m0..m0+255]) into regs; LDS write happens in phase B
    float4 vreg[8];
#pragma unroll
    for (int i=0;i<8;++i){
      int s = t + 256*i; int vd = s >> 5, c16 = s & 31;
      vreg[i] = *(const float4*)(Vb + (size_t)vd*2048 + m0 + c16*8);
    }

    f32x4 acc[4][4] = {};

    auto stageP = [&](int kc){
      const int cb = kc & 1, k0 = kc*32;
      __builtin_amdgcn_global_load_lds(AS1C(Pblk + (size_t)prow*2048 + k0 + pk16*8),
                                       AS3(Pbuf + cb*2048 + w*512), 16, 0, 0);
#pragma unroll
      for (int i=0;i<4;++i){
        int row = i*64 + prow;
        __builtin_amdgcn_global_load_lds(AS1C(RhT + (size_t)(m0 + row)*2048 + k0 + pk16*8),
                                         AS3(Rbuf + cb*8192 + i*2048 + w*512), 16, 0, 0);
      }
    };

    stageP(0);
#pragma unroll 2
    for (int kc = 0; kc < 64; ++kc){
      __syncthreads();                 // chunk kc staged (vmcnt drained by barrier)
      if (kc < 63) stageP(kc+1);
      const int cb = kc & 1;
      const f16* Pb = Pbuf + cb*2048;
      const f16* Rb = Rbuf + cb*8192;
      f16x8 af[4], bf[4];
#pragma unroll
      for (int ti=0;ti<4;++ti) af[ti] = *(const f16x8*)(Pb + (16*ti + lr)*32 + q*8);
#pragma unroll
      for (int tj=0;tj<4;++tj) bf[tj] = *(const f16x8*)(Rb + (w*64 + 16*tj + lr)*32 + q*8);
#pragma unroll
      for (int ti=0;ti<4;++ti)
#pragma unroll
        for (int tj=0;tj<4;++tj)
          acc[ti][tj] = __builtin_amdgcn_mfma_f32_16x16x32_f16(af[ti], bf[tj], acc[ti][tj], 0,0,0);
    }

    // ---- phase B: online softmax (rows wave-local via shuffle within 16-lane groups)
    float pm[4][4];
#pragma unroll
    for (int ti=0;ti<4;++ti)
#pragma unroll
      for (int r=0;r<4;++r)
        pm[ti][r] = fmaxf(fmaxf(acc[ti][0][r], acc[ti][1][r]),
                          fmaxf(acc[ti][2][r], acc[ti][3][r]));
#pragma unroll
    for (int mm=1;mm<16;mm<<=1)
#pragma unroll
      for (int ti=0;ti<4;++ti)
#pragma unroll
        for (int r=0;r<4;++r)
          pm[ti][r] = fmaxf(pm[ti][r], __shfl_xor(pm[ti][r], mm));
    if (lr == 0){
#pragma unroll
      for (int ti=0;ti<4;++ti)
#pragma unroll
        for (int r=0;r<4;++r)
          stat_max[(16*ti + 4*q + r)*4 + w] = pm[ti][r];
    }
    __syncthreads();  // B1: per-wave col maxima visible

    float Mn[4][4], mo[4][4], ps[4][4], al[4];
#pragma unroll
    for (int ti=0;ti<4;++ti)
#pragma unroll
      for (int r=0;r<4;++r){
        int row = 16*ti + 4*q + r;
        float4 s4 = *(const float4*)&stat_max[row*4];
        float tm = fmaxf(fmaxf(s4.x, s4.y), fmaxf(s4.z, s4.w));
        mo[ti][r] = mrow[row];
        Mn[ti][r] = fmaxf(mo[ti][r], tm);
        ps[ti][r] = 0.0f;
        if (ti == w) al[r] = __expf(mo[ti][r] - Mn[ti][r]);  // alpha for my O rows
      }
#pragma unroll
    for (int ti=0;ti<4;++ti)
#pragma unroll
      for (int tj=0;tj<4;++tj)
#pragma unroll
        for (int r=0;r<4;++r){
          float e = __expf(acc[ti][tj][r] - Mn[ti][r]);
          ps[ti][r] += e;
          El[(16*ti + 4*q + r)*264 + w*64 + 16*tj + lr] = (f16)e;
        }
#pragma unroll
    for (int mm=1;mm<16;mm<<=1)
#pragma unroll
      for (int ti=0;ti<4;++ti)
#pragma unroll
        for (int r=0;r<4;++r)
          ps[ti][r] += __shfl_xor(ps[ti][r], mm);
    if (lr == 0){
#pragma unroll
      for (int ti=0;ti<4;++ti)
#pragma unroll
        for (int r=0;r<4;++r)
          stat_sum[(16*ti + 4*q + r)*4 + w] = ps[ti][r];
    }
    // rescale running O by alpha (uses pre-update mrow, consistent with E)
#pragma unroll
    for (int r=0;r<4;++r)
#pragma unroll
      for (int tj=0;tj<4;++tj)
        Oacc[tj][r] *= al[r];
    // V tile regs -> LDS (padded stride 264 halves)
#pragma unroll
    for (int i=0;i<8;++i){
      int s = t + 256*i; int vd = s >> 5, c16 = s & 31;
      *(float4*)(Vl + vd*264 + c16*8) = vreg[i];
    }
    __syncthreads();  // B2: El, Vl, stat_sum visible

    if (t < 64){  // update running stats (same arithmetic as per-lane Mn)
      float4 ssv = *(const float4*)&stat_sum[t*4];
      float4 smv = *(const float4*)&stat_max[t*4];
      float s4 = ssv.x + ssv.y + ssv.z + ssv.w;
      float tm = fmaxf(fmaxf(smv.x, smv.y), fmaxf(smv.z, smv.w));
      float mo2 = mrow[t];
      float Mn2 = fmaxf(mo2, tm);
      float a2  = __expf(mo2 - Mn2);
      lrow[t] = lrow[t]*a2 + s4;
      mrow[t] = Mn2;
    }

    // ---- E @ V : O[16w..16w+15][0..63] += E[rows][256] * V[256][64]
#pragma unroll
    for (int ks=0; ks<8; ++ks){
      f16x8 ae = *(const f16x8*)(El + (16*w + lr)*264 + ks*32 + q*8);
#pragma unroll
      for (int tj=0;tj<4;++tj){
        f16x8 bv = *(const f16x8*)(Vl + (16*tj + lr)*264 + ks*32 + q*8);
        Oacc[tj] = __builtin_amdgcn_mfma_f32_16x16x32_f16(ae, bv, Oacc[tj], 0,0,0);
      }
    }
  }

  __syncthreads();  // final lrow visible
#pragma unroll
  for (int tj=0;tj<4;++tj)
#pragma unroll
    for (int r=0;r<4;++r){
      int row = 16*w + 4*q + r;
      int col = 16*tj + lr;
      out[((size_t)b*2048 + n0 + row)*64 + col] = Oacc[tj][r] / lrow[row];
    }
}

extern "C" void kernel_launch(void* const* d_in, const int* in_sizes, int n_in,
                              void* d_out, int out_size, void* d_ws, size_t ws_size,
                              hipStream_t stream){
  (void)in_sizes; (void)n_in; (void)out_size; (void)ws_size;
  const float* Q  = (const float*)d_in[0];
  const float* K  = (const float*)d_in[1];
  const float* V  = (const float*)d_in[2];
  const float* Dm = (const float*)d_in[3];
  float* out = (float*)d_out;
  char* ws = (char*)d_ws;
  f16* Ph  = (f16*)ws;                                   // 64 MB
  f16* RhT = (f16*)(ws + (size_t)64*1024*1024);          //  8 MB
  f16* VhT = (f16*)(ws + (size_t)72*1024*1024);          //  2 MB

  hipFuncSetAttribute(reinterpret_cast<const void*>(k_attn),
                      hipFuncAttributeMaxDynamicSharedMemorySize, 111104);

  k_rescaleT<<<dim3(32,32), 256, 0, stream>>>(Dm, RhT);
  k_vT      <<<dim3(32,8),  256, 0, stream>>>(V, VhT);
  k_qk      <<<dim3(16,16,8), 256, 0, stream>>>(Q, K, Ph);
  k_attn    <<<dim3(32,8),  256, 111104, stream>>>(Ph, RhT, VhT, out);
}

// Round 2
// 379.276 us; speedup vs baseline: 1.2403x; 1.2403x over previous
//
#include <hip/hip_runtime.h>

// ScaledDotProductAttention: context = softmax(relu(Q K^T) @ R / 8) @ V
// B=8, N=2048, D=64. R = (1+e)/(1+exp(1-dist)), shared across batch.
//
// ws layout (needs >= 74 MB):
//   [0,   64MB)  Ph  : fp16 relu(QK^T)*0.125, [B][N][N]
//   [64MB,72MB)  RhT : fp16 R^T, [j][m]
//   [72MB,74MB)  VhT : fp16 V^T, [B][64][N]

typedef _Float16 f16;
typedef _Float16 f16x8 __attribute__((ext_vector_type(8)));
typedef float    f32x4 __attribute__((ext_vector_type(4)));

#define AS1C(p) ((const __attribute__((address_space(1))) void*)(p))
#define AS3(p)  ((__attribute__((address_space(3))) void*)(p))

__device__ __forceinline__ f16x8 cvt_f16x8(float4 a, float4 b){
  f16x8 v;
  v[0]=(f16)a.x; v[1]=(f16)a.y; v[2]=(f16)a.z; v[3]=(f16)a.w;
  v[4]=(f16)b.x; v[5]=(f16)b.y; v[6]=(f16)b.z; v[7]=(f16)b.w;
  return v;
}

// ---------------- kernel 0a: RhT[j][m] = rescale(dist[m][j]) in fp16 -------
__global__ void k_rescaleT(const float* __restrict__ Dm, f16* __restrict__ RhT){
  __shared__ f16 tl[64][65];
  const int k0 = blockIdx.x*64, m0 = blockIdx.y*64;
  const int t = threadIdx.x, c = t & 63, g = t >> 6;
#pragma unroll
  for (int i=0;i<16;++i){
    int k = g*16 + i;
    float d = Dm[(size_t)(k0 + k)*2048 + m0 + c];
    tl[k][c] = (f16)(3.7182818284590452f / (1.0f + __expf(1.0f - d)));
  }
  __syncthreads();
#pragma unroll
  for (int i=0;i<16;++i){
    int m = g*16 + i;
    RhT[(size_t)(m0 + m)*2048 + k0 + c] = tl[c][m];
  }
}

// ---------------- kernel 0b: VhT[b][d][m] = V[b][m][d] in fp16 -------------
__global__ void k_vT(const float* __restrict__ V, f16* __restrict__ VhT){
  __shared__ f16 tl[64][65];
  const int b = blockIdx.y, m0 = blockIdx.x*64;
  const int t = threadIdx.x, c = t & 63, g = t >> 6;
#pragma unroll
  for (int i=0;i<16;++i){
    int m = g*16 + i;
    tl[m][c] = (f16)V[((size_t)b*2048 + m0 + m)*64 + c];
  }
  __syncthreads();
#pragma unroll
  for (int i=0;i<16;++i){
    int d = g*16 + i;
    VhT[((size_t)b*64 + d)*2048 + m0 + c] = tl[c][d];
  }
}

// ---------------- kernel 1: Ph = relu(Q K^T) * 0.125 in fp16 ---------------
// 128x128 tile per WG. Q/K staged to LDS f16 (coalesced 256B row loads,
// stride 72h conflict-free). LDS-transpose epilogue -> coalesced 16B stores.
__launch_bounds__(256, 2)
__global__ void k_qk(const float* __restrict__ Q, const float* __restrict__ Km,
                     f16* __restrict__ Ph){
  __shared__ char shm[36864];
  f16* Qt = (f16*)shm;            // [128][72]
  f16* Kt = (f16*)(shm + 18432);  // [128][72]
  f16* Tt = (f16*)shm;            // [128][136] aliases Qt/Kt after compute

  const int t = threadIdx.x, w = t>>6, l = t&63, lr = l&15, q = l>>4;
  const int b = blockIdx.z, n0 = blockIdx.y*128, m0 = blockIdx.x*128;
  const int wr = (w>>1)*64, wc = (w&1)*64;
  const float* Qb = Q  + ((size_t)b*2048 + n0)*64;
  const float* Kb = Km + ((size_t)b*2048 + m0)*64;

  const int sr = t>>3, sc = t&7;
#pragma unroll
  for (int j=0;j<4;++j){
    int row = sr + 32*j;
    const float* p  = Qb + (size_t)row*64 + sc*8;
    *(f16x8*)(Qt + row*72 + sc*8) = cvt_f16x8(*(const float4*)p, *(const float4*)(p+4));
    const float* pk = Kb + (size_t)row*64 + sc*8;
    *(f16x8*)(Kt + row*72 + sc*8) = cvt_f16x8(*(const float4*)pk, *(const float4*)(pk+4));
  }
  __syncthreads();

  f32x4 acc[4][4] = {};
#pragma unroll
  for (int kc=0;kc<2;++kc){
    f16x8 af[4], bf[4];
#pragma unroll
    for (int ti=0;ti<4;++ti) af[ti] = *(const f16x8*)(Qt + (wr+16*ti+lr)*72 + kc*32 + q*8);
#pragma unroll
    for (int tj=0;tj<4;++tj) bf[tj] = *(const f16x8*)(Kt + (wc+16*tj+lr)*72 + kc*32 + q*8);
#pragma unroll
    for (int ti=0;ti<4;++ti)
#pragma unroll
      for (int tj=0;tj<4;++tj)
        acc[ti][tj] = __builtin_amdgcn_mfma_f32_16x16x32_f16(af[ti], bf[tj], acc[ti][tj], 0,0,0);
  }
  __syncthreads();   // done reading Qt/Kt before Tt overwrite
#pragma unroll
  for (int ti=0;ti<4;++ti)
#pragma unroll
    for (int tj=0;tj<4;++tj)
#pragma unroll
      for (int r=0;r<4;++r)
        Tt[(wr+16*ti+4*q+r)*136 + wc+16*tj+lr] = (f16)(fmaxf(acc[ti][tj][r],0.f)*0.125f);
  __syncthreads();
  const int g16 = t&15, r0 = t>>4;
#pragma unroll
  for (int j=0;j<8;++j){
    int row = r0 + 16*j;
    *(f16x8*)(Ph + ((size_t)b*2048 + n0 + row)*2048 + m0 + g16*8) =
        *(const f16x8*)(Tt + row*136 + g16*8);
  }
}

// ---------------- kernel 2: flash attention over precomputed scores --------
// Per WG (512 thr, 8 waves): 64 Q-rows, 4 j-tiles of 512. S-tile = Ph @ RhT,
// m-chunks of 32 staged via swizzled global_load_lds (double buffered).
// Each wave: 64 rows x 64 cols of the S-tile. Online softmax in registers.
// E@V: wave = 16 rows x 32 cols of O; V frags direct from global (L2-res).
// LDS: Pbuf 8K | Rbuf 64K | El 65K | stats 4.5K = 144896 B.
__launch_bounds__(512, 2)
__global__ void k_attn(const f16* __restrict__ Ph, const f16* __restrict__ RhT,
                       const f16* __restrict__ VhT, float* __restrict__ out){
  extern __shared__ char smem[];
  f16*  Pbuf = (f16*)smem;                       // [2][64][32]
  f16*  Rbuf = (f16*)(smem + 8192);              // [2][512][32]
  f16*  El   = (f16*)(smem + 73728);             // [64][520]
  float* stat_max = (float*)(smem + 140288);     // [64][8]
  float* stat_sum = (float*)(smem + 142336);     // [64][8]
  float* mrow = (float*)(smem + 144384);         // [64]
  float* lrow = (float*)(smem + 144640);         // [64]

  const int t = threadIdx.x, w = t>>6, l = t&63, lr = l&15, q = l>>4;
  const int b = blockIdx.y, n0 = blockIdx.x*64;
  const int wm = w & 3, wd = w >> 2;             // O decomposition: rows 16*wm, cols 32*wd

  const f16* Pblk = Ph  + ((size_t)b*2048 + n0)*2048;
  const f16* Vb   = VhT + (size_t)b*64*2048;

  if (t < 64){ mrow[t] = -1e30f; lrow[t] = 0.0f; }

  f32x4 Oacc[2] = {};
  const int sA = (q ^ ((lr>>1)&3))*8;            // read-side XOR swizzle

  auto stage = [&](int jb, int kc){
    const int cb = kc & 1, k0 = kc*32;
    if (w < 4){
      int row = t >> 2;                          // P row 0..63
      int gs = ((t & 3) ^ ((row >> 1) & 3)) * 8; // fetch-side XOR swizzle
      __builtin_amdgcn_global_load_lds(AS1C(Pblk + (size_t)row*2048 + k0 + gs),
                                       AS3(Pbuf + cb*2048 + w*512), 16, 0, 0);
    }
#pragma unroll
    for (int i=0;i<4;++i){
      int rb = i*8 + w;                          // 16-row block 0..31
      int row = rb*16 + (l>>2);                  // j-local row 0..511
      int gs = ((l & 3) ^ ((row >> 1) & 3)) * 8;
      __builtin_amdgcn_global_load_lds(AS1C(RhT + (size_t)(jb + row)*2048 + k0 + gs),
                                       AS3(Rbuf + cb*16384 + rb*512), 16, 0, 0);
    }
  };

  stage(0, 0);

  for (int mt = 0; mt < 4; ++mt){
    const int jb = mt*512;
    f32x4 acc[4][4] = {};

#pragma unroll 2
    for (int kc = 0; kc < 64; ++kc){
      __syncthreads();                           // chunk kc staged
      if (kc < 63)      stage(jb, kc+1);
      else if (mt < 3)  stage(jb + 512, 0);
      const int cb = kc & 1;
      const f16* Pb = Pbuf + cb*2048;
      const f16* Rb = Rbuf + cb*16384;
      f16x8 af[4], bf[4];
#pragma unroll
      for (int ti=0;ti<4;++ti) af[ti] = *(const f16x8*)(Pb + (16*ti + lr)*32 + sA);
#pragma unroll
      for (int tj=0;tj<4;++tj) bf[tj] = *(const f16x8*)(Rb + (w*64 + 16*tj + lr)*32 + sA);
#pragma unroll
      for (int ti=0;ti<4;++ti)
#pragma unroll
        for (int tj=0;tj<4;++tj)
          acc[ti][tj] = __builtin_amdgcn_mfma_f32_16x16x32_f16(af[ti], bf[tj], acc[ti][tj], 0,0,0);
    }

    // ---- online softmax ----
    float pm[4][4];
#pragma unroll
    for (int ti=0;ti<4;++ti)
#pragma unroll
      for (int r=0;r<4;++r)
        pm[ti][r] = fmaxf(fmaxf(acc[ti][0][r], acc[ti][1][r]),
                          fmaxf(acc[ti][2][r], acc[ti][3][r]));
#pragma unroll
    for (int mm=1;mm<16;mm<<=1)
#pragma unroll
      for (int ti=0;ti<4;++ti)
#pragma unroll
        for (int r=0;r<4;++r)
          pm[ti][r] = fmaxf(pm[ti][r], __shfl_xor(pm[ti][r], mm));
    if (lr == 0)
#pragma unroll
      for (int ti=0;ti<4;++ti)
#pragma unroll
        for (int r=0;r<4;++r)
          stat_max[(16*ti + 4*q + r)*8 + w] = pm[ti][r];
    __syncthreads();                             // B1: per-wave maxima visible

    float Mn[4][4], ps[4][4], al[4];
#pragma unroll
    for (int ti=0;ti<4;++ti)
#pragma unroll
      for (int r=0;r<4;++r){
        int row = 16*ti + 4*q + r;
        float4 sa = *(const float4*)&stat_max[row*8];
        float4 sb = *(const float4*)&stat_max[row*8+4];
        float tm = fmaxf(fmaxf(fmaxf(sa.x,sa.y),fmaxf(sa.z,sa.w)),
                         fmaxf(fmaxf(sb.x,sb.y),fmaxf(sb.z,sb.w)));
        float mo = mrow[row];
        float M  = fmaxf(mo, tm);
        Mn[ti][r] = M;
        ps[ti][r] = 0.f;
        if (ti == wm) al[r] = __expf(mo - M);
      }
#pragma unroll
    for (int ti=0;ti<4;++ti)
#pragma unroll
      for (int tj=0;tj<4;++tj)
#pragma unroll
        for (int r=0;r<4;++r){
          float e = __expf(acc[ti][tj][r] - Mn[ti][r]);
          ps[ti][r] += e;
          El[(16*ti + 4*q + r)*520 + w*64 + 16*tj + lr] = (f16)e;
        }
#pragma unroll
    for (int mm=1;mm<16;mm<<=1)
#pragma unroll
      for (int ti=0;ti<4;++ti)
#pragma unroll
        for (int r=0;r<4;++r)
          ps[ti][r] += __shfl_xor(ps[ti][r], mm);
    if (lr == 0)
#pragma unroll
      for (int ti=0;ti<4;++ti)
#pragma unroll
        for (int r=0;r<4;++r)
          stat_sum[(16*ti + 4*q + r)*8 + w] = ps[ti][r];
#pragma unroll
    for (int r=0;r<4;++r){                       // rescale running O (pre-update mrow)
      Oacc[0][r] *= al[r];
      Oacc[1][r] *= al[r];
    }
    __syncthreads();                             // B2: El + stat_sum visible

    if (t < 64){                                 // update running stats
      float m_o = mrow[t], tm = -1e30f, s8 = 0.f;
#pragma unroll
      for (int i=0;i<8;++i){ tm = fmaxf(tm, stat_max[t*8+i]); s8 += stat_sum[t*8+i]; }
      float M = fmaxf(m_o, tm);
      lrow[t] = lrow[t]*__expf(m_o - M) + s8;
      mrow[t] = M;
    }

    // ---- E @ V : O[16wm..+15][32wd..+31] += E[rows][512] * V[512][cols]
    const f16* Ea  = El + (16*wm + lr)*520 + q*8;
    const f16* Vp0 = Vb + (size_t)(32*wd + lr)*2048 + jb + q*8;
    const f16* Vp1 = Vp0 + (size_t)16*2048;
    f16x8 b0 = *(const f16x8*)Vp0, b1 = *(const f16x8*)Vp1;
#pragma unroll
    for (int ks=0; ks<16; ++ks){
      f16x8 nb0, nb1;
      if (ks < 15){ nb0 = *(const f16x8*)(Vp0 + (ks+1)*32); nb1 = *(const f16x8*)(Vp1 + (ks+1)*32); }
      f16x8 ae = *(const f16x8*)(Ea + ks*32);
      Oacc[0] = __builtin_amdgcn_mfma_f32_16x16x32_f16(ae, b0, Oacc[0], 0,0,0);
      Oacc[1] = __builtin_amdgcn_mfma_f32_16x16x32_f16(ae, b1, Oacc[1], 0,0,0);
      b0 = nb0; b1 = nb1;
    }
  }

  __syncthreads();                               // final lrow visible
#pragma unroll
  for (int tj=0;tj<2;++tj)
#pragma unroll
    for (int r=0;r<4;++r){
      int row = 16*wm + 4*q + r;
      int col = 32*wd + 16*tj + lr;
      out[((size_t)b*2048 + n0 + row)*64 + col] = Oacc[tj][r] / lrow[row];
    }
}

extern "C" void kernel_launch(void* const* d_in, const int* in_sizes, int n_in,
                              void* d_out, int out_size, void* d_ws, size_t ws_size,
                              hipStream_t stream){
  (void)in_sizes; (void)n_in; (void)out_size; (void)ws_size;
  const float* Q  = (const float*)d_in[0];
  const float* K  = (const float*)d_in[1];
  const float* V  = (const float*)d_in[2];
  const float* Dm = (const float*)d_in[3];
  float* out = (float*)d_out;
  char* ws = (char*)d_ws;
  f16* Ph  = (f16*)ws;                                   // 64 MB
  f16* RhT = (f16*)(ws + (size_t)64*1024*1024);          //  8 MB
  f16* VhT = (f16*)(ws + (size_t)72*1024*1024);          //  2 MB

  hipFuncSetAttribute(reinterpret_cast<const void*>(k_attn),
                      hipFuncAttributeMaxDynamicSharedMemorySize, 144896);

  k_rescaleT<<<dim3(32,32), 256, 0, stream>>>(Dm, RhT);
  k_vT      <<<dim3(32,8),  256, 0, stream>>>(V, VhT);
  k_qk      <<<dim3(16,16,8), 256, 0, stream>>>(Q, K, Ph);
  k_attn    <<<dim3(32,8),  512, 144896, stream>>>(Ph, RhT, VhT, out);
}

// Round 3
// 307.692 us; speedup vs baseline: 1.5289x; 1.2326x over previous
//
#include <hip/hip_runtime.h>

// ScaledDotProductAttention: context = softmax(relu(Q K^T) @ R / 8) @ V
// B=8, N=2048, D=64. R = (1+e)/(1+exp(1-dist)), shared across batch.
//
// ws layout (needs >= 83 MB):
//   [0,   64MB)  Ph  : fp16 relu(QK^T)*0.125, [B][N][N]
//   [64MB,72MB)  RhT : fp16 R^T, [j][m]
//   [72MB,74MB)  VhT : fp16 V^T, [B][64][N]
//   [74MB,82MB)  Op  : fp32 partial O, [256 wg][128][64]
//   [82MB, +128K) mp : fp32 partial rowmax, [256][128]
//   [.., +128K)   lp : fp32 partial rowsum, [256][128]

typedef _Float16 f16;
typedef _Float16 f16x8 __attribute__((ext_vector_type(8)));
typedef float    f32x4 __attribute__((ext_vector_type(4)));

#define AS1C(p) ((const __attribute__((address_space(1))) void*)(p))
#define AS3(p)  ((__attribute__((address_space(3))) void*)(p))

__device__ __forceinline__ f16x8 cvt_f16x8(float4 a, float4 b){
  f16x8 v;
  v[0]=(f16)a.x; v[1]=(f16)a.y; v[2]=(f16)a.z; v[3]=(f16)a.w;
  v[4]=(f16)b.x; v[5]=(f16)b.y; v[6]=(f16)b.z; v[7]=(f16)b.w;
  return v;
}

// ---------------- kernel 0a: RhT[j][m] = rescale(dist[m][j]) in fp16 -------
__global__ void k_rescaleT(const float* __restrict__ Dm, f16* __restrict__ RhT){
  __shared__ f16 tl[64][65];
  const int k0 = blockIdx.x*64, m0 = blockIdx.y*64;
  const int t = threadIdx.x, c = t & 63, g = t >> 6;
#pragma unroll
  for (int i=0;i<16;++i){
    int k = g*16 + i;
    float d = Dm[(size_t)(k0 + k)*2048 + m0 + c];
    tl[k][c] = (f16)(3.7182818284590452f / (1.0f + __expf(1.0f - d)));
  }
  __syncthreads();
#pragma unroll
  for (int i=0;i<16;++i){
    int m = g*16 + i;
    RhT[(size_t)(m0 + m)*2048 + k0 + c] = tl[c][m];
  }
}

// ---------------- kernel 0b: VhT[b][d][m] = V[b][m][d] in fp16 -------------
__global__ void k_vT(const float* __restrict__ V, f16* __restrict__ VhT){
  __shared__ f16 tl[64][65];
  const int b = blockIdx.y, m0 = blockIdx.x*64;
  const int t = threadIdx.x, c = t & 63, g = t >> 6;
#pragma unroll
  for (int i=0;i<16;++i){
    int m = g*16 + i;
    tl[m][c] = (f16)V[((size_t)b*2048 + m0 + m)*64 + c];
  }
  __syncthreads();
#pragma unroll
  for (int i=0;i<16;++i){
    int d = g*16 + i;
    VhT[((size_t)b*64 + d)*2048 + m0 + c] = tl[c][d];
  }
}

// ---------------- kernel 1: Ph = relu(Q K^T) * 0.125 in fp16 ---------------
__launch_bounds__(256, 2)
__global__ void k_qk(const float* __restrict__ Q, const float* __restrict__ Km,
                     f16* __restrict__ Ph){
  __shared__ char shm[36864];
  f16* Qt = (f16*)shm;            // [128][72]
  f16* Kt = (f16*)(shm + 18432);  // [128][72]
  f16* Tt = (f16*)shm;            // [128][136] aliases Qt/Kt after compute

  const int t = threadIdx.x, w = t>>6, l = t&63, lr = l&15, q = l>>4;
  const int b = blockIdx.z, n0 = blockIdx.y*128, m0 = blockIdx.x*128;
  const int wr = (w>>1)*64, wc = (w&1)*64;
  const float* Qb = Q  + ((size_t)b*2048 + n0)*64;
  const float* Kb = Km + ((size_t)b*2048 + m0)*64;

  const int sr = t>>3, sc = t&7;
#pragma unroll
  for (int j=0;j<4;++j){
    int row = sr + 32*j;
    const float* p  = Qb + (size_t)row*64 + sc*8;
    *(f16x8*)(Qt + row*72 + sc*8) = cvt_f16x8(*(const float4*)p, *(const float4*)(p+4));
    const float* pk = Kb + (size_t)row*64 + sc*8;
    *(f16x8*)(Kt + row*72 + sc*8) = cvt_f16x8(*(const float4*)pk, *(const float4*)(pk+4));
  }
  __syncthreads();

  f32x4 acc[4][4] = {};
#pragma unroll
  for (int kc=0;kc<2;++kc){
    f16x8 af[4], bf[4];
#pragma unroll
    for (int ti=0;ti<4;++ti) af[ti] = *(const f16x8*)(Qt + (wr+16*ti+lr)*72 + kc*32 + q*8);
#pragma unroll
    for (int tj=0;tj<4;++tj) bf[tj] = *(const f16x8*)(Kt + (wc+16*tj+lr)*72 + kc*32 + q*8);
#pragma unroll
    for (int ti=0;ti<4;++ti)
#pragma unroll
      for (int tj=0;tj<4;++tj)
        acc[ti][tj] = __builtin_amdgcn_mfma_f32_16x16x32_f16(af[ti], bf[tj], acc[ti][tj], 0,0,0);
  }
  __syncthreads();
#pragma unroll
  for (int ti=0;ti<4;++ti)
#pragma unroll
    for (int tj=0;tj<4;++tj)
#pragma unroll
      for (int r=0;r<4;++r)
        Tt[(wr+16*ti+4*q+r)*136 + wc+16*tj+lr] = (f16)(fmaxf(acc[ti][tj][r],0.f)*0.125f);
  __syncthreads();
  const int g16 = t&15, r0 = t>>4;
#pragma unroll
  for (int j=0;j<8;++j){
    int row = r0 + 16*j;
    *(f16x8*)(Ph + ((size_t)b*2048 + n0 + row)*2048 + m0 + g16*8) =
        *(const f16x8*)(Tt + row*136 + g16*8);
  }
}

// ---------------- kernel 2: split-j flash attention over scores ------------
// Grid 256 = 16 n-blocks x 8 batches x 2 j-halves; jh = bid&1 so each j-half
// maps to one XCD parity -> its 4 MB R-half is XCD-L2-resident.
// Per WG (512 thr): 128 Q-rows, j-half 1024 as 4 mt-tiles of 256.
// Per m-chunk(32): stage P 8K + R 16K via swizzled global_load_lds (dbuf).
// Phase-A wave tile 64x64 (waves 2 row-halves x 4 j-quarters).
// E@V: wave = 16 O-rows x 64 cols; V frags direct from global (L2-res).
// Partial O/m/l written to ws; k_comb merges the 2 j-halves.
// LDS: Pbuf 16K | Rbuf 32K | El 67.6K | stats 5.1K = 121856 B.
__launch_bounds__(512, 2)
__global__ void k_attn(const f16* __restrict__ Ph, const f16* __restrict__ RhT,
                       const f16* __restrict__ VhT, float* __restrict__ Op,
                       float* __restrict__ mp, float* __restrict__ lp){
  extern __shared__ char smem[];
  f16*  Pbuf = (f16*)smem;                      // [2][128][32]
  f16*  Rbuf = (f16*)(smem + 16384);            // [2][256][32]
  f16*  El   = (f16*)(smem + 49152);            // [128][264]
  float* stat_max = (float*)(smem + 116736);    // [128][4]
  float* stat_sum = (float*)(smem + 118784);    // [128][4]
  float* mrow = (float*)(smem + 120832);        // [128]
  float* lrow = (float*)(smem + 121344);        // [128]

  const int t = threadIdx.x, w = t>>6, l = t&63, lr = l&15, q = l>>4;
  const int bid = blockIdx.x;
  const int jh = bid & 1, nbb = bid >> 1, b = nbb & 7, nb = nbb >> 3;
  const int n0 = nb*128, jbase = jh*1024;
  const int wr = (w>>2)*64, wc = (w&3)*64;

  const f16* Pblk = Ph  + ((size_t)b*2048 + n0)*2048;
  const f16* Vb   = VhT + (size_t)b*64*2048;

  if (t < 128){ mrow[t] = -1e30f; lrow[t] = 0.0f; }

  f32x4 Oacc[4] = {};                           // O rows 16w..+15, cols 16tj+lr
  const int sA = (q ^ ((lr>>1)&3))*8;           // read-side XOR swizzle
  const int prow = t>>2, pg = t&3;
  const int psw = (pg ^ ((prow>>1)&3))*8;       // fetch-side swizzle (P)

  auto stage = [&](int jg, int kc){
    const int cb = kc & 1, k0 = kc*32;
    __builtin_amdgcn_global_load_lds(AS1C(Pblk + (size_t)prow*2048 + k0 + psw),
                                     AS3(Pbuf + cb*4096 + w*512), 16, 0, 0);
#pragma unroll
    for (int i=0;i<2;++i){
      int slot = i*512 + t;
      int row = slot>>2, g = slot&3;
      int gs = (g ^ ((row>>1)&3))*8;
      __builtin_amdgcn_global_load_lds(AS1C(RhT + (size_t)(jg + row)*2048 + k0 + gs),
                                       AS3(Rbuf + cb*8192 + i*4096 + w*512), 16, 0, 0);
    }
  };

  stage(jbase, 0);

  for (int mt = 0; mt < 4; ++mt){
    const int jg = jbase + mt*256;
    f32x4 acc[4][4] = {};

#pragma unroll 2
    for (int kc = 0; kc < 64; ++kc){
      __syncthreads();                          // chunk kc staged
      if (kc < 63)      stage(jg, kc+1);
      else if (mt < 3)  stage(jg + 256, 0);
      const int cb = kc & 1;
      const f16* Pb = Pbuf + cb*4096;
      const f16* Rb = Rbuf + cb*8192;
      f16x8 af[4], bf[4];
#pragma unroll
      for (int ti=0;ti<4;++ti) af[ti] = *(const f16x8*)(Pb + (wr + 16*ti + lr)*32 + sA);
#pragma unroll
      for (int tj=0;tj<4;++tj) bf[tj] = *(const f16x8*)(Rb + (wc + 16*tj + lr)*32 + sA);
#pragma unroll
      for (int ti=0;ti<4;++ti)
#pragma unroll
        for (int tj=0;tj<4;++tj)
          acc[ti][tj] = __builtin_amdgcn_mfma_f32_16x16x32_f16(af[ti], bf[tj], acc[ti][tj], 0,0,0);
    }

    // ---- online softmax ----
    float pm[4][4];
#pragma unroll
    for (int ti=0;ti<4;++ti)
#pragma unroll
      for (int r=0;r<4;++r)
        pm[ti][r] = fmaxf(fmaxf(acc[ti][0][r], acc[ti][1][r]),
                          fmaxf(acc[ti][2][r], acc[ti][3][r]));
#pragma unroll
    for (int mm=1;mm<16;mm<<=1)
#pragma unroll
      for (int ti=0;ti<4;++ti)
#pragma unroll
        for (int r=0;r<4;++r)
          pm[ti][r] = fmaxf(pm[ti][r], __shfl_xor(pm[ti][r], mm));
    if (lr == 0)
#pragma unroll
      for (int ti=0;ti<4;++ti)
#pragma unroll
        for (int r=0;r<4;++r)
          stat_max[(wr + 16*ti + 4*q + r)*4 + (w&3)] = pm[ti][r];
    __syncthreads();                            // B1

    float Mn[4][4], ps[4][4], al[4];
#pragma unroll
    for (int ti=0;ti<4;++ti)
#pragma unroll
      for (int r=0;r<4;++r){
        int row = wr + 16*ti + 4*q + r;
        float4 s4 = *(const float4*)&stat_max[row*4];
        float tm = fmaxf(fmaxf(s4.x,s4.y), fmaxf(s4.z,s4.w));
        float mo = mrow[row];
        float M  = fmaxf(mo, tm);
        Mn[ti][r] = M;
        ps[ti][r] = 0.f;
        if (ti == (w&3)) al[r] = __expf(mo - M);
      }
#pragma unroll
    for (int ti=0;ti<4;++ti)
#pragma unroll
      for (int tj=0;tj<4;++tj)
#pragma unroll
        for (int r=0;r<4;++r){
          float e = __expf(acc[ti][tj][r] - Mn[ti][r]);
          ps[ti][r] += e;
          El[(wr + 16*ti + 4*q + r)*264 + wc + 16*tj + lr] = (f16)e;
        }
#pragma unroll
    for (int mm=1;mm<16;mm<<=1)
#pragma unroll
      for (int ti=0;ti<4;++ti)
#pragma unroll
        for (int r=0;r<4;++r)
          ps[ti][r] += __shfl_xor(ps[ti][r], mm);
    if (lr == 0)
#pragma unroll
      for (int ti=0;ti<4;++ti)
#pragma unroll
        for (int r=0;r<4;++r)
          stat_sum[(wr + 16*ti + 4*q + r)*4 + (w&3)] = ps[ti][r];
#pragma unroll
    for (int r=0;r<4;++r)
#pragma unroll
      for (int tj=0;tj<4;++tj)
        Oacc[tj][r] *= al[r];                   // rescale running O
    __syncthreads();                            // B2: El + stat_sum visible

    if (t < 128){
      float m_o = mrow[t], tm = -1e30f, s4 = 0.f;
#pragma unroll
      for (int i=0;i<4;++i){ tm = fmaxf(tm, stat_max[t*4+i]); s4 += stat_sum[t*4+i]; }
      float M = fmaxf(m_o, tm);
      lrow[t] = lrow[t]*__expf(m_o - M) + s4;
      mrow[t] = M;
    }

    // ---- E @ V : O[16w..+15][64] += E[16 rows][256] * V[256][64]
    const f16* Ep = El + (16*w + lr)*264 + q*8;
    const f16* Vp = Vb + (size_t)lr*2048 + jg + q*8;
    f16x8 vb0[4];
#pragma unroll
    for (int tj=0;tj<4;++tj) vb0[tj] = *(const f16x8*)(Vp + tj*16*2048);
#pragma unroll
    for (int ks=0; ks<8; ++ks){
      f16x8 vn[4];
      if (ks < 7)
#pragma unroll
        for (int tj=0;tj<4;++tj) vn[tj] = *(const f16x8*)(Vp + tj*16*2048 + (ks+1)*32);
      f16x8 ae = *(const f16x8*)(Ep + ks*32);
#pragma unroll
      for (int tj=0;tj<4;++tj)
        Oacc[tj] = __builtin_amdgcn_mfma_f32_16x16x32_f16(ae, vb0[tj], Oacc[tj], 0,0,0);
#pragma unroll
      for (int tj=0;tj<4;++tj) vb0[tj] = vn[tj];
    }
  }

  __syncthreads();                              // final mrow/lrow visible
#pragma unroll
  for (int tj=0;tj<4;++tj)
#pragma unroll
    for (int r=0;r<4;++r){
      int row = 16*w + 4*q + r;
      int col = 16*tj + lr;
      Op[((size_t)bid*128 + row)*64 + col] = Oacc[tj][r];
    }
  if (t < 128){ mp[bid*128 + t] = mrow[t]; lp[bid*128 + t] = lrow[t]; }
}

// ---------------- kernel 3: combine the 2 j-half partials ------------------
__global__ void k_comb(const float* __restrict__ Op, const float* __restrict__ mp,
                       const float* __restrict__ lp, float* __restrict__ out){
  const int rb = blockIdx.x;                    // 0..127 = nb*8 + b
  const int b = rb & 7, nb = rb >> 3;
  const int bid0 = rb*2, bid1 = rb*2 + 1;
  const int t = threadIdx.x;
  const int rr = t >> 4, ci = t & 15;
#pragma unroll
  for (int i=0;i<8;++i){
    int row = rr + 16*i;
    float m0 = mp[bid0*128 + row], m1 = mp[bid1*128 + row];
    float l0 = lp[bid0*128 + row], l1 = lp[bid1*128 + row];
    float M = fmaxf(m0, m1);
    float a0 = __expf(m0 - M), a1 = __expf(m1 - M);
    float inv = 1.0f / (a0*l0 + a1*l1);
    float4 o0 = *(const float4*)&Op[((size_t)bid0*128 + row)*64 + ci*4];
    float4 o1 = *(const float4*)&Op[((size_t)bid1*128 + row)*64 + ci*4];
    float4 o;
    o.x = (a0*o0.x + a1*o1.x)*inv;
    o.y = (a0*o0.y + a1*o1.y)*inv;
    o.z = (a0*o0.z + a1*o1.z)*inv;
    o.w = (a0*o0.w + a1*o1.w)*inv;
    *(float4*)&out[((size_t)b*2048 + nb*128 + row)*64 + ci*4] = o;
  }
}

extern "C" void kernel_launch(void* const* d_in, const int* in_sizes, int n_in,
                              void* d_out, int out_size, void* d_ws, size_t ws_size,
                              hipStream_t stream){
  (void)in_sizes; (void)n_in; (void)out_size; (void)ws_size;
  const float* Q  = (const float*)d_in[0];
  const float* K  = (const float*)d_in[1];
  const float* V  = (const float*)d_in[2];
  const float* Dm = (const float*)d_in[3];
  float* out = (float*)d_out;
  char* ws = (char*)d_ws;
  f16* Ph  = (f16*)ws;                                   // 64 MB
  f16* RhT = (f16*)(ws + (size_t)64*1024*1024);          //  8 MB
  f16* VhT = (f16*)(ws + (size_t)72*1024*1024);          //  2 MB
  float* Op = (float*)(ws + (size_t)74*1024*1024);       //  8 MB
  float* mpp = (float*)(ws + (size_t)82*1024*1024);      // 128 KB
  float* lpp = (float*)(ws + (size_t)82*1024*1024 + 131072);

  hipFuncSetAttribute(reinterpret_cast<const void*>(k_attn),
                      hipFuncAttributeMaxDynamicSharedMemorySize, 121856);

  k_rescaleT<<<dim3(32,32), 256, 0, stream>>>(Dm, RhT);
  k_vT      <<<dim3(32,8),  256, 0, stream>>>(V, VhT);
  k_qk      <<<dim3(16,16,8), 256, 0, stream>>>(Q, K, Ph);
  k_attn    <<<dim3(256),   512, 121856, stream>>>(Ph, RhT, VhT, Op, mpp, lpp);
  k_comb    <<<dim3(128),   256, 0, stream>>>(Op, mpp, lpp, out);
}